// Round 1
// 990.774 us; speedup vs baseline: 1.0911x; 1.0911x over previous
//
#include <hip/hip_runtime.h>
#include <hip/hip_bf16.h>
#include <cstdint>
#include <cstddef>

// Problem constants
#define T_DIM 128
#define B_DIM 64
#define E_DIM 1024
#define H_DIM 1024
#define V_DIM 10000
#define L_DIM 2
#define VP2   10240      // V padded to 80 tiles of 128 (= 40 tiles of 256)
#define MROWS 8192       // T*B rows, t-major (row = t*64 + b) = 64 tiles exactly
#define WN    2097152    // L*H*E = 2^21 (per-weight-array element count)
#define WL    1048576    // per-layer weight stride (H*E)

typedef __bf16 bf16_t;
typedef bf16_t bf16x8 __attribute__((ext_vector_type(8)));
typedef bf16_t bf16x4 __attribute__((ext_vector_type(4)));
typedef float  f32x4  __attribute__((ext_vector_type(4)));

__device__ __forceinline__ void g2l16(const void* g, void* l) {
  __builtin_amdgcn_global_load_lds((const __attribute__((address_space(1))) void*)g,
                                   (__attribute__((address_space(3))) void*)l,
                                   16, 0, 0);
}

__device__ __forceinline__ float fast_tanh(float v) {
  v = fminf(15.f, fmaxf(-15.f, v));
  float e = __expf(2.f * v);
  return (e - 1.f) / (e + 1.f);
}

// ---------------------------------------------------------------------------
// gemm256_bt: C = A @ B^T + bias, fp32 strided output. 256x256 tile, BK=32,
// 512 threads (8 waves, 2x4), 3-deep LDS ring (120KB), counted vmcnt(5),
// single raw s_barrier per K-tile, 2 MFMA phases of 16, setprio around MFMA.
// LDS rows padded to 80B (odd 16B-stride -> conflict-free ds_read_b128).
// Staging: A+B tile = 2560 16B chunks = exactly 5 global_load_lds calls.
// ---------------------------------------------------------------------------
__global__ __launch_bounds__(512, 2)
void gemm256_bt(const bf16_t* __restrict__ A, const bf16_t* __restrict__ Bm, int K,
                const float* __restrict__ bias, int Nvalid,
                float* __restrict__ outf, long stride_t, int stride_b, int BNT)
{
  constexpr int RS  = 80;          // LDS row stride bytes (64 data + 16 pad)
  constexpr int ASZ = 256 * RS;    // 20480 B per matrix per buffer
  constexpr int BUF = 2 * ASZ;     // 40960 B per ring slot
  __shared__ alignas(16) char lds[3 * BUF];   // 122880 B

  const int tid  = threadIdx.x;
  const int wid  = tid >> 6;
  const int lane = tid & 63;
  const int wr = wid >> 2;          // 0..1 : wave row (128 rows each)
  const int wc = wid & 3;           // 0..3 : wave col (64 cols each)
  const int fr = lane & 15;
  const int fq = (lane >> 4) * 16;  // byte offset of 8-elem k-chunk

  // XCD-stripe swizzle (gridDim.x % 8 == 0 required; bm fast within stripe)
  int g   = blockIdx.x;
  int SM  = (gridDim.x / BNT) >> 3;
  int xcd = g & 7;
  int q   = g >> 3;
  int bm  = xcd * SM + (q % SM);
  int bn  = q / SM;

  // staging map: chunk c = u*512 + tid; c<1280 -> A, else B.
  // within matrix: row r = cl/5, 16B-chunk qq = cl%5 (qq==4 is the pad slot).
  const bf16_t* gsrc[5];
  int loff[5];
#pragma unroll
  for (int u = 0; u < 5; ++u) {
    int c   = u * 512 + tid;
    int isB = (c >= 1280) ? 1 : 0;
    int cl  = isB ? (c - 1280) : c;
    int r = cl / 5, qq = cl % 5;
    if (qq == 4) qq = 0;                        // pad chunk: harmless dup load
    const bf16_t* base = isB ? (Bm + (size_t)(bn * 256 + r) * K)
                             : (A  + (size_t)(bm * 256 + r) * K);
    gsrc[u] = base + qq * 8;
    loff[u] = c * 16;                           // linear LDS dest (wave-uniform + lane*16)
  }

  int aoff[8], boff[4];
#pragma unroll
  for (int i = 0; i < 8; ++i) aoff[i] = (wr * 128 + i * 16 + fr) * RS + fq;
#pragma unroll
  for (int i = 0; i < 4; ++i) boff[i] = ASZ + (wc * 64 + i * 16 + fr) * RS + fq;

  f32x4 zero = {0.f, 0.f, 0.f, 0.f};
  f32x4 acc[8][4];
#pragma unroll
  for (int i = 0; i < 8; ++i)
#pragma unroll
    for (int j = 0; j < 4; ++j) acc[i][j] = zero;

  const int NT = K >> 5;            // K-tiles of 32

  // prologue: stage tiles 0 and 1 into slots 0,1
#pragma unroll
  for (int u = 0; u < 5; ++u) g2l16(gsrc[u],      lds + loff[u]);
#pragma unroll
  for (int u = 0; u < 5; ++u) g2l16(gsrc[u] + 32, lds + BUF + loff[u]);

  for (int t = 0; t < NT; ++t) {
    // own staging for tile t complete (5 calls of t+1 may stay in flight)
    if (t < NT - 1) asm volatile("s_waitcnt vmcnt(5)" ::: "memory");
    else            asm volatile("s_waitcnt vmcnt(0)" ::: "memory");
    __builtin_amdgcn_sched_barrier(0);
    __builtin_amdgcn_s_barrier();   // all waves' tile-t data visible; slot (t+2)%3 free
    asm volatile("" ::: "memory");
    __builtin_amdgcn_sched_barrier(0);

    char* cbuf = lds + (t % 3) * BUF;
    char* sbuf = lds + ((t + 2) % 3) * BUF;
    const int  k2 = (t + 2) << 5;
    const bool st = (t + 2) < NT;

    bf16x8 bfv[4], af[4];
    // ---- phase A: B frags + A frags 0-3, stage 3 calls, 16 MFMA ----
#pragma unroll
    for (int i = 0; i < 4; ++i) bfv[i] = *(const bf16x8*)(cbuf + boff[i]);
#pragma unroll
    for (int i = 0; i < 4; ++i) af[i]  = *(const bf16x8*)(cbuf + aoff[i]);
    if (st) {
      g2l16(gsrc[0] + k2, sbuf + loff[0]);
      g2l16(gsrc[1] + k2, sbuf + loff[1]);
      g2l16(gsrc[2] + k2, sbuf + loff[2]);
    }
    asm volatile("s_waitcnt lgkmcnt(0)" ::: "memory");
    __builtin_amdgcn_sched_barrier(0);
    __builtin_amdgcn_s_setprio(1);
#pragma unroll
    for (int mi = 0; mi < 4; ++mi)
#pragma unroll
      for (int ni = 0; ni < 4; ++ni)
        acc[mi][ni] = __builtin_amdgcn_mfma_f32_16x16x32_bf16(af[mi], bfv[ni], acc[mi][ni], 0, 0, 0);
    __builtin_amdgcn_s_setprio(0);

    // ---- phase B: A frags 4-7, stage 2 calls, 16 MFMA ----
#pragma unroll
    for (int i = 0; i < 4; ++i) af[i] = *(const bf16x8*)(cbuf + aoff[4 + i]);
    if (st) {
      g2l16(gsrc[3] + k2, sbuf + loff[3]);
      g2l16(gsrc[4] + k2, sbuf + loff[4]);
    }
    asm volatile("s_waitcnt lgkmcnt(0)" ::: "memory");
    __builtin_amdgcn_sched_barrier(0);
    __builtin_amdgcn_s_setprio(1);
#pragma unroll
    for (int mi = 0; mi < 4; ++mi)
#pragma unroll
      for (int ni = 0; ni < 4; ++ni)
        acc[4 + mi][ni] = __builtin_amdgcn_mfma_f32_16x16x32_bf16(af[mi], bfv[ni], acc[4 + mi][ni], 0, 0, 0);
    __builtin_amdgcn_s_setprio(0);
  }

  // epilogue: C/D layout col=lane&15, row=(lane>>4)*4+reg (m89-verified)
  const int rb  = (lane >> 4) * 4;
  const int cb_ = lane & 15;
#pragma unroll
  for (int mi = 0; mi < 8; ++mi) {
#pragma unroll
    for (int ni = 0; ni < 4; ++ni) {
      const int col = bn * 256 + wc * 64 + ni * 16 + cb_;
      if (col < Nvalid) {
        const float bv = bias[col];
#pragma unroll
        for (int r = 0; r < 4; ++r) {
          const int row = bm * 256 + wr * 128 + mi * 16 + rb + r;
          long o = (long)(row >> 6) * stride_t + (long)(row & 63) * stride_b + col;
          outf[o] = acc[mi][ni][r] + bv;
        }
      }
    }
  }
}

// ---------------------------------------------------------------------------
// 128x128 m97-structure GEMM (kept for per-layer + step-0 chains)
// ---------------------------------------------------------------------------
template<int BK>
__global__ __launch_bounds__(256)
void gemm_bt(const bf16_t* __restrict__ A, const bf16_t* __restrict__ Bm, int K,
             const float* __restrict__ bias, int Nvalid,
             const float* __restrict__ Z, int do_tanh,
             bf16_t* __restrict__ outb, int outb_stride,
             float* __restrict__ outf, long stride_t, int stride_b, int Mvalid,
             int BNT, long abatch, long bbatch, long biasbatch, long obatch)
{
  __shared__ alignas(16) bf16_t lA[128 * BK];
  __shared__ alignas(16) bf16_t lB[128 * BK];
  const int tid  = threadIdx.x;
  const int wid  = tid >> 6;
  const int lane = tid & 63;

  int bm, bn;
  if (BNT > 0) {
    int g   = blockIdx.x;
    int SM  = (gridDim.x / BNT) >> 3;   // bm tiles per XCD stripe
    int xcd = g & 7;
    int q   = g >> 3;
    bm = xcd * SM + (q % SM);
    bn = q / SM;
  } else {
    bn = blockIdx.x;
    bm = 0;
    int batch = blockIdx.y;
    A    += (size_t)batch * abatch;
    Bm   += (size_t)batch * bbatch;
    bias += (size_t)batch * biasbatch;
    if (outf) outf += (size_t)batch * obatch;
  }

  f32x4 zero = {0.f, 0.f, 0.f, 0.f};
  f32x4 acc[4][4];
#pragma unroll
  for (int i = 0; i < 4; ++i)
#pragma unroll
    for (int j = 0; j < 4; ++j) acc[i][j] = zero;

  constexpr int CW    = BK / 8;            // 16B chunks per row
  constexpr int CALLS = (128 * BK / 8) / 256;
  const bf16_t* gA[CALLS];
  const bf16_t* gB[CALLS];
  int ldsoff[CALLS];
#pragma unroll
  for (int u = 0; u < CALLS; ++u) {
    int chunk = (u * 4 + wid) * 64 + lane;
    int row = chunk / CW, cc = chunk % CW;
    gA[u] = A  + (size_t)(bm * 128 + row) * K + cc * 8;
    gB[u] = Bm + (size_t)(bn * 128 + row) * K + cc * 8;
    ldsoff[u] = chunk * 16;
  }

  const int mrow = (wid >> 1) * 64;   // wave's 64x64 quadrant
  const int ncol = (wid & 1) * 64;
  const int fr = lane & 15;
  const int fq = (lane >> 4) * 16;    // byte offset of 8-elem k-chunk
  char* lAb = (char*)lA;
  char* lBb = (char*)lB;

  for (int k0 = 0; k0 < K; k0 += BK) {
    __syncthreads();
#pragma unroll
    for (int u = 0; u < CALLS; ++u) g2l16(gA[u] + k0, lAb + ldsoff[u]);
#pragma unroll
    for (int u = 0; u < CALLS; ++u) g2l16(gB[u] + k0, lBb + ldsoff[u]);
    __syncthreads();

#pragma unroll
    for (int kk = 0; kk < BK / 32; ++kk) {
      bf16x8 af[4], bfv[4];
#pragma unroll
      for (int t = 0; t < 4; ++t) {
        af[t]  = *(const bf16x8*)(lAb + (mrow + t * 16 + fr) * (2 * BK) + kk * 64 + fq);
        bfv[t] = *(const bf16x8*)(lBb + (ncol + t * 16 + fr) * (2 * BK) + kk * 64 + fq);
      }
#pragma unroll
      for (int tm = 0; tm < 4; ++tm)
#pragma unroll
        for (int tn = 0; tn < 4; ++tn)
          acc[tm][tn] = __builtin_amdgcn_mfma_f32_16x16x32_bf16(af[tm], bfv[tn], acc[tm][tn], 0, 0, 0);
    }
  }

  const int rb = (lane >> 4) * 4;
  const int cb = lane & 15;
#pragma unroll
  for (int tm = 0; tm < 4; ++tm) {
#pragma unroll
    for (int tn = 0; tn < 4; ++tn) {
      const int col = bn * 128 + ncol + tn * 16 + cb;
      const float bv = (col < Nvalid) ? bias[col] : 0.f;
#pragma unroll
      for (int r = 0; r < 4; ++r) {
        const int row = bm * 128 + mrow + tm * 16 + rb + r;
        float v = acc[tm][tn][r] + bv;
        if (Z) {
          int zr = (row < 64) ? row : 64 + (row & 63);
          v += Z[zr * 1024 + col];
        }
        if (do_tanh) v = fast_tanh(v);
        if (outb) outb[(size_t)row * outb_stride + col] = (bf16_t)v;
        if (outf && row < Mvalid && col < Nvalid) {
          long o = (long)(row >> 6) * stride_t + (long)(row & 63) * stride_b + col;
          outf[o] = v;
        }
      }
    }
  }
}

// ---- vectorized conversion / gather kernels (x4) ----
__global__ void k_cvt3(const float* __restrict__ a, const float* __restrict__ b,
                       const float* __restrict__ c, bf16_t* __restrict__ da,
                       bf16_t* __restrict__ db, bf16_t* __restrict__ dc) {
  int i = blockIdx.x * 256 + threadIdx.x;   // < 3*WN/4
  int j = i << 2;
  int sel = j >> 21;
  int loc = j & (WN - 1);
  const float* s = (sel == 0) ? a : (sel == 1) ? b : c;
  bf16_t*      d = (sel == 0) ? da : (sel == 1) ? db : dc;
  f32x4 v = *(const f32x4*)(s + loc);
  bf16x4 o;
#pragma unroll
  for (int k = 0; k < 4; ++k) o[k] = (bf16_t)v[k];
  *(bf16x4*)(d + loc) = o;
}

__global__ void k_cvt_dw4(const float* __restrict__ s, bf16_t* __restrict__ d) {
  int i = blockIdx.x * 256 + threadIdx.x;   // < VP2*1024/4
  int j = i << 2;
  int r = j >> 10, c = j & 1023;
  f32x4 v = {0.f, 0.f, 0.f, 0.f};
  if (r < V_DIM) v = *(const f32x4*)(s + (size_t)r * 1024 + c);
  bf16x4 o;
#pragma unroll
  for (int k = 0; k < 4; ++k) o[k] = (bf16_t)v[k];
  *(bf16x4*)(d + j) = o;
}

__global__ void k_gather4(const int* __restrict__ inp, const float* __restrict__ etab,
                          bf16_t* __restrict__ X) {
  int i = blockIdx.x * 256 + threadIdx.x;   // < MROWS*1024/4
  int j = i << 2;
  int r = j >> 10, e = j & 1023;            // r = t*64+b == flat index into inp
  int idx = inp[r];
  f32x4 v = *(const f32x4*)(etab + (size_t)idx * 1024 + e);
  bf16x4 o;
#pragma unroll
  for (int k = 0; k < 4; ++k) o[k] = (bf16_t)v[k];
  *(bf16x4*)(X + j) = o;
}

__global__ void k_cvt_hidden4(const float* __restrict__ hid, bf16_t* __restrict__ d) {
  int i = blockIdx.x * 256 + threadIdx.x;   // < L*128*1024/4
  int j = i << 2;
  int l = j >> 17, r = (j >> 10) & 127, e = j & 1023;
  f32x4 v = {0.f, 0.f, 0.f, 0.f};
  if (r < B_DIM) v = *(const f32x4*)(hid + (size_t)(l * B_DIM + r) * 1024 + e);
  bf16x4 o;
#pragma unroll
  for (int k = 0; k < 4; ++k) o[k] = (bf16_t)v[k];
  *(bf16x4*)(d + j) = o;
}

extern "C" void kernel_launch(void* const* d_in, const int* in_sizes, int n_in,
                              void* d_out, int out_size, void* d_ws, size_t ws_size,
                              hipStream_t stream) {
  const int*   inp    = (const int*)  d_in[0];
  const float* hidden = (const float*)d_in[1];
  const float* etab   = (const float*)d_in[2];
  const float* Ww     = (const float*)d_in[3];
  const float* Wb     = (const float*)d_in[4];
  const float* Uw     = (const float*)d_in[5];
  const float* Ub     = (const float*)d_in[6];
  const float* Fw     = (const float*)d_in[7];
  const float* Fb     = (const float*)d_in[8];
  const float* Dw     = (const float*)d_in[9];
  const float* Db     = (const float*)d_in[10];
  float* out = (float*)d_out;

  // workspace carve (~66 MB)
  char* p = (char*)d_ws;
  auto carve = [&](size_t n) { char* r = p; p += (n + 255) & ~(size_t)255; return r; };
  bf16_t* Wbf  = (bf16_t*)carve((size_t)WN * 2);
  bf16_t* Ubf  = (bf16_t*)carve((size_t)WN * 2);
  bf16_t* Fbf  = (bf16_t*)carve((size_t)WN * 2);
  bf16_t* Dbf  = (bf16_t*)carve((size_t)VP2 * 1024 * 2);
  bf16_t* Xc   = (bf16_t*)carve((size_t)MROWS * 1024 * 2);
  bf16_t* Hc   = (bf16_t*)carve((size_t)MROWS * 1024 * 2);
  bf16_t* hidb = (bf16_t*)carve((size_t)L_DIM * 128 * 1024 * 2);
  bf16_t* h0b  = (bf16_t*)carve((size_t)128 * 1024 * 2);
  float*  Zbuf = (float*) carve((size_t)2 * 128 * 1024 * 4);  // [l][{HU:64, aU:64}][1024]
  float*  Z0 = Zbuf, * Z1 = Zbuf + 131072;

  float* hall = out + (size_t)T_DIM * B_DIM * V_DIM;
  const long ST_H = (long)L_DIM * B_DIM * H_DIM;   // 131072
  const long ST_V = (long)B_DIM * V_DIM;           // 640000

  // prep
  k_cvt3       <<<3 * WN / 4 / 256, 256, 0, stream>>>(Ww, Uw, Fw, Wbf, Ubf, Fbf);
  k_cvt_dw4    <<<VP2 * 1024 / 4 / 256, 256, 0, stream>>>(Dw, Dbf);
  k_gather4    <<<MROWS * 1024 / 4 / 256, 256, 0, stream>>>(inp, etab, Xc);
  k_cvt_hidden4<<<L_DIM * 128 * 1024 / 4 / 256, 256, 0, stream>>>(hidden, hidb);

  // step-0 chain (small, BK=64). HU for both layers batched via grid.y.
  gemm_bt<64><<<dim3(8, 2), 256, 0, stream>>>(hidb, Ubf, 1024,
      Ub, 1024, nullptr, 0, nullptr, 0,
      Zbuf, 0L, 1024, 64,
      0, (long)128 * 1024, (long)WL, 1024L, 131072L);

  for (int l = 0; l < L_DIM; ++l) {
    float* Zl = l ? Z1 : Z0;
    // h0_l = tanh(x0 @ Ww^T + Wb + HU_l)
    gemm_bt<64><<<dim3(8, 1), 256, 0, stream>>>(Xc, Wbf + (size_t)l * WL, 1024,
        Wb + l * 1024, 1024, Zl, 1, h0b, 1024,
        nullptr, 0L, 0, 0, 0, 0, 0, 0, 0);
    // aU_l = h0_l @ Uw^T + Ub  -> Z section rows 64..127
    gemm_bt<64><<<dim3(8, 1), 256, 0, stream>>>(h0b, Ubf + (size_t)l * WL, 1024,
        Ub + l * 1024, 1024, nullptr, 0, nullptr, 0,
        Zl + 64 * 1024, 0L, 1024, 64, 0, 0, 0, 0, 0);
    // H = tanh(X @ Ww^T + Wb + Z) -> Hc + hall
    gemm_bt<32><<<dim3(64 * 8), 256, 0, stream>>>(Xc, Wbf + (size_t)l * WL, 1024,
        Wb + l * 1024, 1024, Zl, 1, Hc, 1024,
        hall + (size_t)l * B_DIM * H_DIM, ST_H, 1024, MROWS,
        8, 0, 0, 0, 0);
    // X = tanh(H @ Fw^T + Fb)
    gemm_bt<32><<<dim3(64 * 8), 256, 0, stream>>>(Hc, Fbf + (size_t)l * WL, 1024,
        Fb + l * 1024, 1024, nullptr, 1, Xc, 1024,
        nullptr, 0L, 0, 0, 8, 0, 0, 0, 0);
  }

  // logits = X @ Dw^T + Db  (256^2 pipelined kernel: 32x40 = 1280 blocks)
  gemm256_bt<<<dim3(32 * 40), 512, 0, stream>>>(Xc, Dbf, 1024,
      Db, V_DIM, out, ST_V, V_DIM, 40);

  (void)in_sizes; (void)n_in; (void)out_size; (void)ws_size;
}

// Round 2
// 989.513 us; speedup vs baseline: 1.0925x; 1.0013x over previous
//
#include <hip/hip_runtime.h>
#include <hip/hip_bf16.h>
#include <cstdint>
#include <cstddef>

// Problem constants
#define T_DIM 128
#define B_DIM 64
#define E_DIM 1024
#define H_DIM 1024
#define V_DIM 10000
#define L_DIM 2
#define VP2   10240      // V padded to 80 tiles of 128 (= 40 tiles of 256)
#define MROWS 8192       // T*B rows, t-major (row = t*64 + b) = 64 tiles exactly
#define WN    2097152    // L*H*E = 2^21 (per-weight-array element count)
#define WL    1048576    // per-layer weight stride (H*E)

typedef __bf16 bf16_t;
typedef bf16_t bf16x8 __attribute__((ext_vector_type(8)));
typedef bf16_t bf16x4 __attribute__((ext_vector_type(4)));
typedef float  f32x4  __attribute__((ext_vector_type(4)));

__device__ __forceinline__ void g2l16(const void* g, void* l) {
  __builtin_amdgcn_global_load_lds((const __attribute__((address_space(1))) void*)g,
                                   (__attribute__((address_space(3))) void*)l,
                                   16, 0, 0);
}

__device__ __forceinline__ float fast_tanh(float v) {
  v = fminf(15.f, fmaxf(-15.f, v));
  float e = __expf(2.f * v);
  return (e - 1.f) / (e + 1.f);
}

// ---------------------------------------------------------------------------
// gemm256_bt: C = A @ B^T + bias, fp32 strided output. 256x256 tile, BK=32,
// 512 threads (8 waves, 2x4 -> per-wave 128x64 output), 4-deep LDS ring
// (4 x 32KB = 128KB), prefetch depth 3 tiles, counted vmcnt(8), single raw
// s_barrier per K-tile, 2 MFMA phases of 16, setprio around MFMA.
//
// LDS layout (per matrix, 256 rows x 64B, NO pad): XOR bank swizzle folded
// into the 128B row-pair: phys 16B-chunk y = ((row&1)<<2 | col16) ^ (row&7),
// addr = (row>>1)*128 + y*16.  ds_read_b128 lanes fr=0..7 then hit all 8
// 16B slots mod 128 -> ~2-way (free).  Staging keeps the LDS dest LINEAR
// (global_load_lds constraint) and applies the INVERSE permutation to the
// global source address (within-128B permutation -> same cacheline use).
// A+B tile = 2048 16B chunks = exactly 4 global_load_lds calls, no waste.
// ---------------------------------------------------------------------------
__global__ __launch_bounds__(512, 2)
void gemm256_bt(const bf16_t* __restrict__ A, const bf16_t* __restrict__ Bm, int K,
                const float* __restrict__ bias, int Nvalid,
                float* __restrict__ outf, long stride_t, int stride_b, int BNT)
{
  constexpr int ASZ = 256 * 64;    // 16384 B per matrix per slot
  constexpr int BUF = 2 * ASZ;     // 32768 B per ring slot (A + B)
  __shared__ alignas(16) char lds[4 * BUF];   // 131072 B

  const int tid  = threadIdx.x;
  const int wid  = tid >> 6;
  const int lane = tid & 63;
  const int wr = wid >> 2;          // 0..1 : wave row (128 rows each)
  const int wc = wid & 3;           // 0..3 : wave col (64 cols each)
  const int fr = lane & 15;
  const int fq16 = lane >> 4;       // 16B-chunk index of the k-slice (0..3)

  // XCD-stripe swizzle (gridDim.x % 8 == 0 required; bm fast within stripe)
  int g   = blockIdx.x;
  int SM  = (gridDim.x / BNT) >> 3;
  int xcd = g & 7;
  int q   = g >> 3;
  int bm  = xcd * SM + (q % SM);
  int bn  = q / SM;

  // staging map: chunk c = u*512 + tid; c<1024 -> A, else B.
  // Linear LDS dest (chunk c -> byte c*16); global source inverse-swizzled:
  //   cm = c&1023; rp = cm>>3; y = cm&7; u3 = y ^ ((rp&3)<<1);
  //   r0 = (u3>>2)&1; row = rp*2+r0; col16 = (u3&3)^r0.
  const bf16_t* gsrc[4];
  int loff[4];
#pragma unroll
  for (int u = 0; u < 4; ++u) {
    int c   = u * 512 + tid;
    int isB = c >> 10;
    int cm  = c & 1023;
    int rp  = cm >> 3, y = cm & 7;
    int u3  = y ^ ((rp & 3) << 1);
    int r0  = (u3 >> 2) & 1;
    int row = rp * 2 + r0;
    int col16 = (u3 & 3) ^ r0;
    const bf16_t* base = isB ? (Bm + (size_t)(bn * 256 + row) * K)
                             : (A  + (size_t)(bm * 256 + row) * K);
    gsrc[u] = base + col16 * 8;
    loff[u] = c * 16;
  }

  // swizzled read offsets (16B-aligned): addr = (row>>1)*128 + y*16
  int aoff[8], boff[4];
#pragma unroll
  for (int i = 0; i < 8; ++i) {
    int row = wr * 128 + i * 16 + fr;
    int y   = (((row & 1) << 2) | fq16) ^ (row & 7);
    aoff[i] = (row >> 1) * 128 + y * 16;
  }
#pragma unroll
  for (int i = 0; i < 4; ++i) {
    int row = wc * 64 + i * 16 + fr;
    int y   = (((row & 1) << 2) | fq16) ^ (row & 7);
    boff[i] = ASZ + (row >> 1) * 128 + y * 16;
  }

  f32x4 zero = {0.f, 0.f, 0.f, 0.f};
  f32x4 acc[8][4];
#pragma unroll
  for (int i = 0; i < 8; ++i)
#pragma unroll
    for (int j = 0; j < 4; ++j) acc[i][j] = zero;

  const int NT = K >> 5;            // K-tiles of 32 (NT >= 4)

  // prologue: stage tiles 0,1,2 into slots 0,1,2 (12 loads outstanding)
#pragma unroll
  for (int u = 0; u < 4; ++u) g2l16(gsrc[u],      lds + 0 * BUF + loff[u]);
#pragma unroll
  for (int u = 0; u < 4; ++u) g2l16(gsrc[u] + 32, lds + 1 * BUF + loff[u]);
#pragma unroll
  for (int u = 0; u < 4; ++u) g2l16(gsrc[u] + 64, lds + 2 * BUF + loff[u]);

  for (int t = 0; t < NT; ++t) {
    // own staging for tile t complete; up to 8 younger loads stay in flight
    if      (t < NT - 2) asm volatile("s_waitcnt vmcnt(8)" ::: "memory");
    else if (t == NT - 2) asm volatile("s_waitcnt vmcnt(4)" ::: "memory");
    else                  asm volatile("s_waitcnt vmcnt(0)" ::: "memory");
    __builtin_amdgcn_sched_barrier(0);
    __builtin_amdgcn_s_barrier();   // tile-t data visible; slot (t+3)%4 free
    asm volatile("" ::: "memory");
    __builtin_amdgcn_sched_barrier(0);

    char* cbuf = lds + (t & 3) * BUF;
    char* sbuf = lds + ((t + 3) & 3) * BUF;
    const int  k3 = (t + 3) << 5;
    const bool st = (t + 3) < NT;

    bf16x8 bfv[4], af[4];
    // ---- phase A: B frags + A frags 0-3, stage 2 calls, 16 MFMA ----
#pragma unroll
    for (int i = 0; i < 4; ++i) bfv[i] = *(const bf16x8*)(cbuf + boff[i]);
#pragma unroll
    for (int i = 0; i < 4; ++i) af[i]  = *(const bf16x8*)(cbuf + aoff[i]);
    if (st) {
      g2l16(gsrc[0] + k3, sbuf + loff[0]);
      g2l16(gsrc[1] + k3, sbuf + loff[1]);
    }
    asm volatile("s_waitcnt lgkmcnt(0)" ::: "memory");
    __builtin_amdgcn_sched_barrier(0);
    __builtin_amdgcn_s_setprio(1);
#pragma unroll
    for (int mi = 0; mi < 4; ++mi)
#pragma unroll
      for (int ni = 0; ni < 4; ++ni)
        acc[mi][ni] = __builtin_amdgcn_mfma_f32_16x16x32_bf16(af[mi], bfv[ni], acc[mi][ni], 0, 0, 0);
    __builtin_amdgcn_s_setprio(0);

    // ---- phase B: A frags 4-7, stage 2 calls, 16 MFMA ----
#pragma unroll
    for (int i = 0; i < 4; ++i) af[i] = *(const bf16x8*)(cbuf + aoff[4 + i]);
    if (st) {
      g2l16(gsrc[2] + k3, sbuf + loff[2]);
      g2l16(gsrc[3] + k3, sbuf + loff[3]);
    }
    asm volatile("s_waitcnt lgkmcnt(0)" ::: "memory");
    __builtin_amdgcn_sched_barrier(0);
    __builtin_amdgcn_s_setprio(1);
#pragma unroll
    for (int mi = 0; mi < 4; ++mi)
#pragma unroll
      for (int ni = 0; ni < 4; ++ni)
        acc[4 + mi][ni] = __builtin_amdgcn_mfma_f32_16x16x32_bf16(af[mi], bfv[ni], acc[4 + mi][ni], 0, 0, 0);
    __builtin_amdgcn_s_setprio(0);
  }

  // epilogue: C/D layout col=lane&15, row=(lane>>4)*4+reg (m89-verified)
  const int rb  = (lane >> 4) * 4;
  const int cb_ = lane & 15;
#pragma unroll
  for (int mi = 0; mi < 8; ++mi) {
#pragma unroll
    for (int ni = 0; ni < 4; ++ni) {
      const int col = bn * 256 + wc * 64 + ni * 16 + cb_;
      if (col < Nvalid) {
        const float bv = bias[col];
#pragma unroll
        for (int r = 0; r < 4; ++r) {
          const int row = bm * 256 + wr * 128 + mi * 16 + rb + r;
          long o = (long)(row >> 6) * stride_t + (long)(row & 63) * stride_b + col;
          outf[o] = acc[mi][ni][r] + bv;
        }
      }
    }
  }
}

// ---------------------------------------------------------------------------
// 128x128 m97-structure GEMM (kept for per-layer + step-0 chains)
// ---------------------------------------------------------------------------
template<int BK>
__global__ __launch_bounds__(256)
void gemm_bt(const bf16_t* __restrict__ A, const bf16_t* __restrict__ Bm, int K,
             const float* __restrict__ bias, int Nvalid,
             const float* __restrict__ Z, int do_tanh,
             bf16_t* __restrict__ outb, int outb_stride,
             float* __restrict__ outf, long stride_t, int stride_b, int Mvalid,
             int BNT, long abatch, long bbatch, long biasbatch, long obatch)
{
  __shared__ alignas(16) bf16_t lA[128 * BK];
  __shared__ alignas(16) bf16_t lB[128 * BK];
  const int tid  = threadIdx.x;
  const int wid  = tid >> 6;
  const int lane = tid & 63;

  int bm, bn;
  if (BNT > 0) {
    int g   = blockIdx.x;
    int SM  = (gridDim.x / BNT) >> 3;   // bm tiles per XCD stripe
    int xcd = g & 7;
    int q   = g >> 3;
    bm = xcd * SM + (q % SM);
    bn = q / SM;
  } else {
    bn = blockIdx.x;
    bm = 0;
    int batch = blockIdx.y;
    A    += (size_t)batch * abatch;
    Bm   += (size_t)batch * bbatch;
    bias += (size_t)batch * biasbatch;
    if (outf) outf += (size_t)batch * obatch;
  }

  f32x4 zero = {0.f, 0.f, 0.f, 0.f};
  f32x4 acc[4][4];
#pragma unroll
  for (int i = 0; i < 4; ++i)
#pragma unroll
    for (int j = 0; j < 4; ++j) acc[i][j] = zero;

  constexpr int CW    = BK / 8;            // 16B chunks per row
  constexpr int CALLS = (128 * BK / 8) / 256;
  const bf16_t* gA[CALLS];
  const bf16_t* gB[CALLS];
  int ldsoff[CALLS];
#pragma unroll
  for (int u = 0; u < CALLS; ++u) {
    int chunk = (u * 4 + wid) * 64 + lane;
    int row = chunk / CW, cc = chunk % CW;
    gA[u] = A  + (size_t)(bm * 128 + row) * K + cc * 8;
    gB[u] = Bm + (size_t)(bn * 128 + row) * K + cc * 8;
    ldsoff[u] = chunk * 16;
  }

  const int mrow = (wid >> 1) * 64;   // wave's 64x64 quadrant
  const int ncol = (wid & 1) * 64;
  const int fr = lane & 15;
  const int fq = (lane >> 4) * 16;    // byte offset of 8-elem k-chunk
  char* lAb = (char*)lA;
  char* lBb = (char*)lB;

  for (int k0 = 0; k0 < K; k0 += BK) {
    __syncthreads();
#pragma unroll
    for (int u = 0; u < CALLS; ++u) g2l16(gA[u] + k0, lAb + ldsoff[u]);
#pragma unroll
    for (int u = 0; u < CALLS; ++u) g2l16(gB[u] + k0, lBb + ldsoff[u]);
    __syncthreads();

#pragma unroll
    for (int kk = 0; kk < BK / 32; ++kk) {
      bf16x8 af[4], bfv[4];
#pragma unroll
      for (int t = 0; t < 4; ++t) {
        af[t]  = *(const bf16x8*)(lAb + (mrow + t * 16 + fr) * (2 * BK) + kk * 64 + fq);
        bfv[t] = *(const bf16x8*)(lBb + (ncol + t * 16 + fr) * (2 * BK) + kk * 64 + fq);
      }
#pragma unroll
      for (int tm = 0; tm < 4; ++tm)
#pragma unroll
        for (int tn = 0; tn < 4; ++tn)
          acc[tm][tn] = __builtin_amdgcn_mfma_f32_16x16x32_bf16(af[tm], bfv[tn], acc[tm][tn], 0, 0, 0);
    }
  }

  const int rb = (lane >> 4) * 4;
  const int cb = lane & 15;
#pragma unroll
  for (int tm = 0; tm < 4; ++tm) {
#pragma unroll
    for (int tn = 0; tn < 4; ++tn) {
      const int col = bn * 128 + ncol + tn * 16 + cb;
      const float bv = (col < Nvalid) ? bias[col] : 0.f;
#pragma unroll
      for (int r = 0; r < 4; ++r) {
        const int row = bm * 128 + mrow + tm * 16 + rb + r;
        float v = acc[tm][tn][r] + bv;
        if (Z) {
          int zr = (row < 64) ? row : 64 + (row & 63);
          v += Z[zr * 1024 + col];
        }
        if (do_tanh) v = fast_tanh(v);
        if (outb) outb[(size_t)row * outb_stride + col] = (bf16_t)v;
        if (outf && row < Mvalid && col < Nvalid) {
          long o = (long)(row >> 6) * stride_t + (long)(row & 63) * stride_b + col;
          outf[o] = v;
        }
      }
    }
  }
}

// ---- vectorized conversion / gather kernels (x4) ----
__global__ void k_cvt3(const float* __restrict__ a, const float* __restrict__ b,
                       const float* __restrict__ c, bf16_t* __restrict__ da,
                       bf16_t* __restrict__ db, bf16_t* __restrict__ dc) {
  int i = blockIdx.x * 256 + threadIdx.x;   // < 3*WN/4
  int j = i << 2;
  int sel = j >> 21;
  int loc = j & (WN - 1);
  const float* s = (sel == 0) ? a : (sel == 1) ? b : c;
  bf16_t*      d = (sel == 0) ? da : (sel == 1) ? db : dc;
  f32x4 v = *(const f32x4*)(s + loc);
  bf16x4 o;
#pragma unroll
  for (int k = 0; k < 4; ++k) o[k] = (bf16_t)v[k];
  *(bf16x4*)(d + loc) = o;
}

__global__ void k_cvt_dw4(const float* __restrict__ s, bf16_t* __restrict__ d) {
  int i = blockIdx.x * 256 + threadIdx.x;   // < VP2*1024/4
  int j = i << 2;
  int r = j >> 10, c = j & 1023;
  f32x4 v = {0.f, 0.f, 0.f, 0.f};
  if (r < V_DIM) v = *(const f32x4*)(s + (size_t)r * 1024 + c);
  bf16x4 o;
#pragma unroll
  for (int k = 0; k < 4; ++k) o[k] = (bf16_t)v[k];
  *(bf16x4*)(d + j) = o;
}

__global__ void k_gather4(const int* __restrict__ inp, const float* __restrict__ etab,
                          bf16_t* __restrict__ X) {
  int i = blockIdx.x * 256 + threadIdx.x;   // < MROWS*1024/4
  int j = i << 2;
  int r = j >> 10, e = j & 1023;            // r = t*64+b == flat index into inp
  int idx = inp[r];
  f32x4 v = *(const f32x4*)(etab + (size_t)idx * 1024 + e);
  bf16x4 o;
#pragma unroll
  for (int k = 0; k < 4; ++k) o[k] = (bf16_t)v[k];
  *(bf16x4*)(X + j) = o;
}

__global__ void k_cvt_hidden4(const float* __restrict__ hid, bf16_t* __restrict__ d) {
  int i = blockIdx.x * 256 + threadIdx.x;   // < L*128*1024/4
  int j = i << 2;
  int l = j >> 17, r = (j >> 10) & 127, e = j & 1023;
  f32x4 v = {0.f, 0.f, 0.f, 0.f};
  if (r < B_DIM) v = *(const f32x4*)(hid + (size_t)(l * B_DIM + r) * 1024 + e);
  bf16x4 o;
#pragma unroll
  for (int k = 0; k < 4; ++k) o[k] = (bf16_t)v[k];
  *(bf16x4*)(d + j) = o;
}

extern "C" void kernel_launch(void* const* d_in, const int* in_sizes, int n_in,
                              void* d_out, int out_size, void* d_ws, size_t ws_size,
                              hipStream_t stream) {
  const int*   inp    = (const int*)  d_in[0];
  const float* hidden = (const float*)d_in[1];
  const float* etab   = (const float*)d_in[2];
  const float* Ww     = (const float*)d_in[3];
  const float* Wb     = (const float*)d_in[4];
  const float* Uw     = (const float*)d_in[5];
  const float* Ub     = (const float*)d_in[6];
  const float* Fw     = (const float*)d_in[7];
  const float* Fb     = (const float*)d_in[8];
  const float* Dw     = (const float*)d_in[9];
  const float* Db     = (const float*)d_in[10];
  float* out = (float*)d_out;

  // workspace carve (~66 MB)
  char* p = (char*)d_ws;
  auto carve = [&](size_t n) { char* r = p; p += (n + 255) & ~(size_t)255; return r; };
  bf16_t* Wbf  = (bf16_t*)carve((size_t)WN * 2);
  bf16_t* Ubf  = (bf16_t*)carve((size_t)WN * 2);
  bf16_t* Fbf  = (bf16_t*)carve((size_t)WN * 2);
  bf16_t* Dbf  = (bf16_t*)carve((size_t)VP2 * 1024 * 2);
  bf16_t* Xc   = (bf16_t*)carve((size_t)MROWS * 1024 * 2);
  bf16_t* Hc   = (bf16_t*)carve((size_t)MROWS * 1024 * 2);
  bf16_t* hidb = (bf16_t*)carve((size_t)L_DIM * 128 * 1024 * 2);
  bf16_t* h0b  = (bf16_t*)carve((size_t)128 * 1024 * 2);
  float*  Zbuf = (float*) carve((size_t)2 * 128 * 1024 * 4);  // [l][{HU:64, aU:64}][1024]
  float*  Z0 = Zbuf, * Z1 = Zbuf + 131072;

  float* hall = out + (size_t)T_DIM * B_DIM * V_DIM;
  const long ST_H = (long)L_DIM * B_DIM * H_DIM;   // 131072
  const long ST_V = (long)B_DIM * V_DIM;           // 640000

  // prep
  k_cvt3       <<<3 * WN / 4 / 256, 256, 0, stream>>>(Ww, Uw, Fw, Wbf, Ubf, Fbf);
  k_cvt_dw4    <<<VP2 * 1024 / 4 / 256, 256, 0, stream>>>(Dw, Dbf);
  k_gather4    <<<MROWS * 1024 / 4 / 256, 256, 0, stream>>>(inp, etab, Xc);
  k_cvt_hidden4<<<L_DIM * 128 * 1024 / 4 / 256, 256, 0, stream>>>(hidden, hidb);

  // step-0 chain (small, BK=64). HU for both layers batched via grid.y.
  gemm_bt<64><<<dim3(8, 2), 256, 0, stream>>>(hidb, Ubf, 1024,
      Ub, 1024, nullptr, 0, nullptr, 0,
      Zbuf, 0L, 1024, 64,
      0, (long)128 * 1024, (long)WL, 1024L, 131072L);

  for (int l = 0; l < L_DIM; ++l) {
    float* Zl = l ? Z1 : Z0;
    // h0_l = tanh(x0 @ Ww^T + Wb + HU_l)
    gemm_bt<64><<<dim3(8, 1), 256, 0, stream>>>(Xc, Wbf + (size_t)l * WL, 1024,
        Wb + l * 1024, 1024, Zl, 1, h0b, 1024,
        nullptr, 0L, 0, 0, 0, 0, 0, 0, 0);
    // aU_l = h0_l @ Uw^T + Ub  -> Z section rows 64..127
    gemm_bt<64><<<dim3(8, 1), 256, 0, stream>>>(h0b, Ubf + (size_t)l * WL, 1024,
        Ub + l * 1024, 1024, nullptr, 0, nullptr, 0,
        Zl + 64 * 1024, 0L, 1024, 64, 0, 0, 0, 0, 0);
    // H = tanh(X @ Ww^T + Wb + Z) -> Hc + hall
    gemm_bt<32><<<dim3(64 * 8), 256, 0, stream>>>(Xc, Wbf + (size_t)l * WL, 1024,
        Wb + l * 1024, 1024, Zl, 1, Hc, 1024,
        hall + (size_t)l * B_DIM * H_DIM, ST_H, 1024, MROWS,
        8, 0, 0, 0, 0);
    // X = tanh(H @ Fw^T + Fb)
    gemm_bt<32><<<dim3(64 * 8), 256, 0, stream>>>(Hc, Fbf + (size_t)l * WL, 1024,
        Fb + l * 1024, 1024, nullptr, 1, Xc, 1024,
        nullptr, 0L, 0, 0, 8, 0, 0, 0, 0);
  }

  // logits = X @ Dw^T + Db  (256^2 pipelined kernel: 32x40 = 1280 blocks)
  gemm256_bt<<<dim3(32 * 40), 512, 0, stream>>>(Xc, Dbf, 1024,
      Db, V_DIM, out, ST_V, V_DIM, 40);

  (void)in_sizes; (void)n_in; (void)out_size; (void)ws_size;
}